// Round 1
// baseline (194.221 us; speedup 1.0000x reference)
//
#include <hip/hip_runtime.h>

// Problem constants (from reference setup_inputs)
#define BATCH 16
#define NCLS 19
#define HW (1024 * 2048)           // elements per batch image
#define BLOCKS_PER_BATCH 128
#define THREADS 256
#define VEC_PER_BLOCK (HW / 4 / BLOCKS_PER_BATCH)   // 4096 int4 per block

// Kernel 1: per-block class-presence bitmask over a contiguous chunk of targets.
// grid = BATCH * BLOCKS_PER_BATCH blocks; each block writes ONE partial mask
// (unconditional write -> no zero-init of d_ws needed, no atomics).
__global__ __launch_bounds__(THREADS)
void presence_kernel(const int* __restrict__ targets, unsigned* __restrict__ partial) {
    const int b   = blockIdx.x / BLOCKS_PER_BATCH;
    const int blk = blockIdx.x % BLOCKS_PER_BATCH;

    const int4* tv = (const int4*)targets;
    const long long base = (long long)b * (HW / 4) + (long long)blk * VEC_PER_BLOCK;

    unsigned m = 0;
    // coalesced: consecutive lanes read consecutive 16B int4 -> global_load_dwordx4
    #pragma unroll 4
    for (int i = threadIdx.x; i < VEC_PER_BLOCK; i += THREADS) {
        int4 v = tv[base + i];
        m |= (1u << v.x) | (1u << v.y) | (1u << v.z) | (1u << v.w);
    }

    // wave-64 OR reduction
    #pragma unroll
    for (int off = 32; off; off >>= 1) m |= __shfl_down(m, off);

    __shared__ unsigned sm[THREADS / 64];
    const int lane = threadIdx.x & 63;
    const int wave = threadIdx.x >> 6;
    if (lane == 0) sm[wave] = m;
    __syncthreads();
    if (threadIdx.x == 0) {
        unsigned r = sm[0];
        #pragma unroll
        for (int w = 1; w < THREADS / 64; w++) r |= sm[w];
        partial[blockIdx.x] = r;
    }
}

// Kernel 2: single block. OR-reduce partials -> 16 presence masks, then
// stable BCE-with-logits over the 304 logits, mean, write scalar.
__global__ __launch_bounds__(512)
void loss_kernel(const float* __restrict__ preds, const unsigned* __restrict__ partial,
                 float* __restrict__ out) {
    __shared__ unsigned bm[BATCH];
    __shared__ float red[8];

    const int tid = threadIdx.x;  // 512 threads

    // Reduce 2048 partials: 32 threads per batch, 4 loads each.
    {
        const int b = tid >> 5;       // 0..15
        const int j = tid & 31;
        unsigned m = 0;
        #pragma unroll
        for (int k = 0; k < BLOCKS_PER_BATCH / 32; k++)
            m |= partial[b * BLOCKS_PER_BATCH + j + 32 * k];
        #pragma unroll
        for (int off = 16; off; off >>= 1) m |= __shfl_down(m, off, 32);
        if (j == 0) bm[b] = m;
    }
    __syncthreads();

    float v = 0.0f;
    if (tid < BATCH * NCLS) {
        const int b = tid / NCLS;
        const int c = tid % NCLS;
        const float x = preds[tid];
        const float t = ((bm[b] >> c) & 1u) ? 1.0f : 0.0f;
        // BCE with logits, numerically stable:
        // -(t*logsig(x) + (1-t)*logsig(-x)) = max(x,0) - x*t + log1p(exp(-|x|))
        v = fmaxf(x, 0.0f) - x * t + log1pf(expf(-fabsf(x)));
    }

    // wave-64 sum reduction
    #pragma unroll
    for (int off = 32; off; off >>= 1) v += __shfl_down(v, off);

    const int lane = tid & 63;
    const int wave = tid >> 6;
    if (lane == 0) red[wave] = v;
    __syncthreads();
    if (tid == 0) {
        float s = 0.0f;
        #pragma unroll
        for (int w = 0; w < 8; w++) s += red[w];
        out[0] = s * (1.0f / (float)(BATCH * NCLS));
    }
}

extern "C" void kernel_launch(void* const* d_in, const int* in_sizes, int n_in,
                              void* d_out, int out_size, void* d_ws, size_t ws_size,
                              hipStream_t stream) {
    const float* preds   = (const float*)d_in[0];   // [16, 19] fp32 logits
    const int*   targets = (const int*)d_in[1];     // [16, 1024, 2048] int32
    unsigned*    partial = (unsigned*)d_ws;         // BATCH*BLOCKS_PER_BATCH uints = 8 KB
    float*       out     = (float*)d_out;           // scalar fp32

    presence_kernel<<<BATCH * BLOCKS_PER_BATCH, THREADS, 0, stream>>>(targets, partial);
    loss_kernel<<<1, 512, 0, stream>>>(preds, partial, out);
}

// Round 3
// 181.694 us; speedup vs baseline: 1.0689x; 1.0689x over previous
//
#include <hip/hip_runtime.h>

// Problem constants (from reference setup_inputs)
#define BATCH 16
#define NCLS 19
#define HW (1024 * 2048)            // elements per batch image
#define BLOCKS_PER_BATCH 128
#define THREADS 256
#define VEC_PER_BLOCK (HW / 4 / BLOCKS_PER_BATCH)   // 4096 int4 per block
#define ITERS (VEC_PER_BLOCK / THREADS)             // 16 int4 per thread

typedef int iv4 __attribute__((ext_vector_type(4)));  // clang vector: OK for nontemporal builtin

// Kernel 1: per-block class-presence bitmask over a contiguous chunk of targets.
// 2048 blocks x 256 thr = 8192 waves = full device wave capacity.
// Each thread issues 16 independent nontemporal int4 loads (256 B) up front
// for maximum memory-level parallelism, then ORs presence bits.
__global__ __launch_bounds__(THREADS)
void presence_kernel(const int* __restrict__ targets, unsigned* __restrict__ partial) {
    const int b   = blockIdx.x >> 7;          // / BLOCKS_PER_BATCH
    const int blk = blockIdx.x & (BLOCKS_PER_BATCH - 1);

    const iv4* tv = (const iv4*)targets
                  + (long long)b * (HW / 4)
                  + (long long)blk * VEC_PER_BLOCK
                  + threadIdx.x;

    iv4 v[ITERS];
    #pragma unroll
    for (int i = 0; i < ITERS; i++)
        v[i] = __builtin_nontemporal_load(&tv[i * THREADS]);   // 16 loads in flight

    unsigned m = 0;
    #pragma unroll
    for (int i = 0; i < ITERS; i++)
        m |= (1u << v[i].x) | (1u << v[i].y) | (1u << v[i].z) | (1u << v[i].w);

    // wave-64 OR reduction
    #pragma unroll
    for (int off = 32; off; off >>= 1) m |= __shfl_down(m, off);

    __shared__ unsigned sm[THREADS / 64];
    const int lane = threadIdx.x & 63;
    const int wave = threadIdx.x >> 6;
    if (lane == 0) sm[wave] = m;
    __syncthreads();
    if (threadIdx.x == 0) {
        unsigned r = sm[0];
        #pragma unroll
        for (int w = 1; w < THREADS / 64; w++) r |= sm[w];
        partial[blockIdx.x] = r;   // unconditional write -> no ws zero-init needed
    }
}

// Kernel 2: single block. OR-reduce 2048 partials -> 16 presence masks, then
// stable BCE-with-logits over the 304 logits, mean, write scalar.
__global__ __launch_bounds__(512)
void loss_kernel(const float* __restrict__ preds, const unsigned* __restrict__ partial,
                 float* __restrict__ out) {
    __shared__ unsigned bm[BATCH];
    __shared__ float red[8];

    const int tid = threadIdx.x;  // 512 threads

    // Reduce 2048 partials: 32 threads per batch, 4 loads each.
    {
        const int b = tid >> 5;       // 0..15
        const int j = tid & 31;
        unsigned m = 0;
        #pragma unroll
        for (int k = 0; k < BLOCKS_PER_BATCH / 32; k++)
            m |= partial[b * BLOCKS_PER_BATCH + j + 32 * k];
        #pragma unroll
        for (int off = 16; off; off >>= 1) m |= __shfl_down(m, off, 32);
        if (j == 0) bm[b] = m;
    }
    __syncthreads();

    float v = 0.0f;
    if (tid < BATCH * NCLS) {
        const int b = tid / NCLS;
        const int c = tid % NCLS;
        const float x = preds[tid];
        const float t = ((bm[b] >> c) & 1u) ? 1.0f : 0.0f;
        // BCE with logits, numerically stable:
        // -(t*logsig(x) + (1-t)*logsig(-x)) = max(x,0) - x*t + log1p(exp(-|x|))
        v = fmaxf(x, 0.0f) - x * t + log1pf(expf(-fabsf(x)));
    }

    // wave-64 sum reduction
    #pragma unroll
    for (int off = 32; off; off >>= 1) v += __shfl_down(v, off);

    const int lane = tid & 63;
    const int wave = tid >> 6;
    if (lane == 0) red[wave] = v;
    __syncthreads();
    if (tid == 0) {
        float s = 0.0f;
        #pragma unroll
        for (int w = 0; w < 8; w++) s += red[w];
        out[0] = s * (1.0f / (float)(BATCH * NCLS));
    }
}

extern "C" void kernel_launch(void* const* d_in, const int* in_sizes, int n_in,
                              void* d_out, int out_size, void* d_ws, size_t ws_size,
                              hipStream_t stream) {
    const float* preds   = (const float*)d_in[0];   // [16, 19] fp32 logits
    const int*   targets = (const int*)d_in[1];     // [16, 1024, 2048] int32
    unsigned*    partial = (unsigned*)d_ws;         // 2048 uints = 8 KB
    float*       out     = (float*)d_out;           // scalar fp32

    presence_kernel<<<BATCH * BLOCKS_PER_BATCH, THREADS, 0, stream>>>(targets, partial);
    loss_kernel<<<1, 512, 0, stream>>>(preds, partial, out);
}